// Round 4
// baseline (175.214 us; speedup 1.0000x reference)
//
#include <hip/hip_runtime.h>
#include <stdint.h>

#define TNUM 2048
#define DDIM 1024
#define NEXP 8
#define KSEL 2
#define IDIM 1024
#define TWOI 2048
#define LIMITV 7.0f
#define ALPHAV 1.702f
#define ROWT_MAX 40   // sum_e ceil(n_e/128) <= 32 + 7

typedef __attribute__((ext_vector_type(8))) short bf16x8;
typedef __attribute__((ext_vector_type(4))) float f32x4;

__device__ __forceinline__ unsigned short f2bf(float f) {
  unsigned u = __float_as_uint(f);
  u += 0x7FFF + ((u >> 16) & 1);   // round-to-nearest-even
  return (unsigned short)(u >> 16);
}

// Direct global->LDS async copy, 16B per lane. LDS dest is wave-uniform
// base + lane*16 (m104); global src is per-lane. Cast through uintptr_t to
// get address_space-attributed pointers (CK pattern).
__device__ __forceinline__ void gl2lds16(const void* g, void* l) {
  __builtin_amdgcn_global_load_lds(
      (__attribute__((address_space(1))) unsigned int*)(uintptr_t)g,
      (__attribute__((address_space(3))) unsigned int*)(uintptr_t)l, 16, 0, 0);
}

// Bijective chunked XCD swizzle (m204).
__device__ __forceinline__ int xcd_swz(int bid, int total) {
  int q = total >> 3, r = total & 7;
  int xcd = bid & 7, pos = bid >> 3;
  return (xcd < r ? xcd * (q + 1) : r * (q + 1) + (xcd - r) * q) + pos;
}

// ---------------- K0: fp32 -> bf16 weight conversion ----------------
__global__ __launch_bounds__(256) void k_cvt(const float* __restrict__ src,
                                             unsigned short* __restrict__ dst, int n8) {
  int i = blockIdx.x * blockDim.x + threadIdx.x;
  if (i >= n8) return;
  const float4* s = (const float4*)src;
  float4 a = s[2 * i], b = s[2 * i + 1];
  union { unsigned short us[8]; int4 v; } o;
  o.us[0] = f2bf(a.x); o.us[1] = f2bf(a.y); o.us[2] = f2bf(a.z); o.us[3] = f2bf(a.w);
  o.us[4] = f2bf(b.x); o.us[5] = f2bf(b.y); o.us[6] = f2bf(b.z); o.us[7] = f2bf(b.w);
  ((int4*)dst)[i] = o.v;
}

// ---------------- K1: RMSNorm + gate logits + top-2 ----------------
__global__ __launch_bounds__(256) void k_rms_gate(
    const float* __restrict__ x, const float* __restrict__ norm_w,
    const float* __restrict__ gate_w, const float* __restrict__ gate_b,
    unsigned short* __restrict__ hb, int* __restrict__ tidx,
    float* __restrict__ twt, int* __restrict__ meta) {
  const int t = blockIdx.x, tid = threadIdx.x;
  const int lane = tid & 63, wid = tid >> 6;
  __shared__ float red[4];
  __shared__ float pred[4][NEXP];
  __shared__ float sscale;

  const float4 v = ((const float4*)x)[t * 256 + tid];
  float ss = v.x * v.x + v.y * v.y + v.z * v.z + v.w * v.w;
#pragma unroll
  for (int o = 32; o; o >>= 1) ss += __shfl_down(ss, o);
  if (lane == 0) red[wid] = ss;
  __syncthreads();
  if (tid == 0) {
    float tot = red[0] + red[1] + red[2] + red[3];
    sscale = rsqrtf(tot * (1.0f / DDIM) + 1.1920929e-07f);
  }
  __syncthreads();
  const float sc = sscale;
  const float4 nw = ((const float4*)norm_w)[tid];
  float4 h;
  h.x = v.x * sc * nw.x; h.y = v.y * sc * nw.y;
  h.z = v.z * sc * nw.z; h.w = v.w * sc * nw.w;
  union { unsigned short us[4]; int2 v2; } hp;
  hp.us[0] = f2bf(h.x); hp.us[1] = f2bf(h.y); hp.us[2] = f2bf(h.z); hp.us[3] = f2bf(h.w);
  ((int2*)hb)[t * 256 + tid] = hp.v2;

  float p[NEXP];
#pragma unroll
  for (int e = 0; e < NEXP; ++e) {
    const float4 g = ((const float4*)gate_w)[e * 256 + tid];
    p[e] = h.x * g.x + h.y * g.y + h.z * g.z + h.w * g.w;
  }
#pragma unroll
  for (int e = 0; e < NEXP; ++e) {
#pragma unroll
    for (int o = 32; o; o >>= 1) p[e] += __shfl_down(p[e], o);
  }
  if (lane == 0) {
#pragma unroll
    for (int e = 0; e < NEXP; ++e) pred[wid][e] = p[e];
  }
  __syncthreads();
  if (tid == 0) {
    float lg[NEXP];
#pragma unroll
    for (int e = 0; e < NEXP; ++e)
      lg[e] = pred[0][e] + pred[1][e] + pred[2][e] + pred[3][e] + gate_b[e];
    int i0 = 0; float v0 = lg[0];
#pragma unroll
    for (int e = 1; e < NEXP; ++e) if (lg[e] > v0) { v0 = lg[e]; i0 = e; }
    int i1 = -1; float v1 = -3.4e38f;
#pragma unroll
    for (int e = 0; e < NEXP; ++e) if (e != i0 && lg[e] > v1) { v1 = lg[e]; i1 = e; }
    float e1 = __expf(v1 - v0);
    float w0 = 1.f / (1.f + e1);
    float w1 = e1 * w0;
    tidx[2 * t] = i0; tidx[2 * t + 1] = i1;
    twt[2 * t] = w0; twt[2 * t + 1] = w1;
    atomicAdd(&meta[i0], 1); atomicAdd(&meta[i1], 1);
  }
}

// ---------------- K2: scan + compact tile table ----------------
__global__ void k_scan(int* __restrict__ meta, int* __restrict__ tl) {
  // meta[0..7]=counts, meta[8..16]=offs, meta[17..24]=cursor, meta[25]=ntiles
  int acc = 0, nt = 0;
  for (int e = 0; e < NEXP; ++e) {
    meta[8 + e] = acc; meta[17 + e] = acc;
    int c = meta[e]; acc += c;
    int ntile = (c + 127) >> 7;
    for (int r = 0; r < ntile; ++r) tl[nt++] = (e << 8) | r;
  }
  meta[16] = acc;
  meta[25] = nt;
}

// ---------------- K3: assign slots ----------------
__global__ __launch_bounds__(256) void k_assign(
    const int* __restrict__ tidx, int* __restrict__ meta,
    int* __restrict__ rows, int* __restrict__ sof) {
  int t = blockIdx.x * blockDim.x + threadIdx.x;
  if (t >= TNUM) return;
  for (int k = 0; k < KSEL; ++k) {
    int e = tidx[2 * t + k];
    int pos = atomicAdd(&meta[17 + e], 1);
    rows[pos] = t;
    sof[2 * t + k] = pos;
  }
}

// ---------------- K4: GEMM1 (gathered A via gload_lds) + SwiGLU ----------------
// LDS layout: linear [128][64] bf16, XOR-swizzled via pre-swizzled global
// source column (rule #21): data at lds(r, c) = global(r, c ^ ((r&7)<<3 elems)).
__global__ __launch_bounds__(256, 2) void k_gemm1(
    const unsigned short* __restrict__ hb, const unsigned short* __restrict__ w1b,
    const float* __restrict__ mlp1_b, const int* __restrict__ meta,
    const int* __restrict__ tl, const int* __restrict__ rows,
    unsigned short* __restrict__ actb) {
  const int nt = meta[25];
  const int total = nt * (TWOI / 128);
  const int bid = blockIdx.x;
  if (bid >= total) return;
  const int j = xcd_swz(bid, total);
  const int ct = j / nt;
  const int tile = tl[j - ct * nt];
  const int e = tile >> 8, rt = tile & 255;
  const int offs = meta[8 + e];
  const int n_e = meta[9 + e] - offs;
  const int tid = threadIdx.x, lane = tid & 63, wid = tid >> 6;

  __shared__ unsigned short As[2][128][64];
  __shared__ unsigned short Bs[2][128][64];
  __shared__ int srow[128];
  if (tid < 128) srow[tid] = rows[offs + min(rt * 128 + tid, n_e - 1)];
  __syncthreads();

  // staging geometry: chunk jj covers rows jj*32..+31; this thread owns
  // row rloc within the chunk and 8 swizzled col elems.
  const int rloc = tid >> 3;                         // 0..31
  const int csw  = (((tid & 7) ^ (rloc & 7)) << 3);  // swizzled source col (elems)
  const unsigned short* gA[4];
  const unsigned short* gB[4];
  const unsigned short* w1e = w1b + (size_t)e * TWOI * DDIM;
#pragma unroll
  for (int jj = 0; jj < 4; ++jj) {
    gA[jj] = hb + (size_t)srow[jj * 32 + rloc] * DDIM + csw;
    gB[jj] = w1e + (size_t)(ct * 128 + jj * 32 + rloc) * DDIM + csw;
  }

#define G1_STAGE(BUF, KT)                                                      \
  _Pragma("unroll") for (int jj = 0; jj < 4; ++jj) {                           \
    gl2lds16(gA[jj] + (KT) * 64, &As[BUF][0][0] + jj * 2048 + tid * 8);        \
    gl2lds16(gB[jj] + (KT) * 64, &Bs[BUF][0][0] + jj * 2048 + tid * 8);        \
  }

  f32x4 acc[4][4];
#pragma unroll
  for (int m = 0; m < 4; ++m)
#pragma unroll
    for (int n = 0; n < 4; ++n) acc[m][n] = (f32x4){0.f, 0.f, 0.f, 0.f};

  const int wr = wid >> 1, wc = wid & 1;
  const int lrow = lane & 15, ksub = (lane >> 4) * 8;
  const int NK = DDIM / 64;

  G1_STAGE(0, 0)
  __syncthreads();

  int cur = 0;
  for (int kt = 0; kt < NK; ++kt) {
    if (kt + 1 < NK) { G1_STAGE(cur ^ 1, kt + 1) }
#pragma unroll
    for (int kk = 0; kk < 2; ++kk) {
      bf16x8 af[4], bfr[4];
#pragma unroll
      for (int m = 0; m < 4; ++m) {
        int row = wr * 64 + m * 16 + lrow;
        int chunk = ((kk * 32 + ksub) >> 3) ^ (row & 7);
        af[m] = *(const bf16x8*)&As[cur][row][chunk * 8];
      }
#pragma unroll
      for (int n = 0; n < 4; ++n) {
        int row = wc * 64 + n * 16 + lrow;
        int chunk = ((kk * 32 + ksub) >> 3) ^ (row & 7);
        bfr[n] = *(const bf16x8*)&Bs[cur][row][chunk * 8];
      }
#pragma unroll
      for (int m = 0; m < 4; ++m)
#pragma unroll
        for (int n = 0; n < 4; ++n)
          acc[m][n] = __builtin_amdgcn_mfma_f32_16x16x32_bf16(af[m], bfr[n], acc[m][n], 0, 0, 0);
    }
    __syncthreads();
    cur ^= 1;
  }
#undef G1_STAGE

  const float* b1e = mlp1_b + e * TWOI;
#pragma unroll
  for (int m = 0; m < 4; ++m) {
#pragma unroll
    for (int n = 0; n < 4; ++n) {
      int cg = ct * 128 + wc * 64 + n * 16 + (lane & 15);
      float bias = b1e[cg];
#pragma unroll
      for (int j2 = 0; j2 < 4; ++j2) {
        float val = acc[m][n][j2] + bias;
        float part = __shfl_xor(val, 1);
        int rl = wr * 64 + m * 16 + ((lane >> 4) << 2) + j2;
        if (!(lane & 1)) {
          float glu = fminf(val, LIMITV);
          float lin = fminf(fmaxf(part, -LIMITV), LIMITV);
          float s = 1.f / (1.f + __expf(-ALPHAV * glu));
          float a = glu * s * (lin + 1.f);
          if (rt * 128 + rl < n_e)
            actb[(size_t)(offs + rt * 128 + rl) * IDIM + (cg >> 1)] = f2bf(a);
        }
      }
    }
  }
}

// ---------------- K5: GEMM2 (contiguous A via gload_lds) ----------------
__global__ __launch_bounds__(256, 2) void k_gemm2(
    const unsigned short* __restrict__ actb, const unsigned short* __restrict__ w2b,
    const float* __restrict__ mlp2_b, const int* __restrict__ meta,
    const int* __restrict__ tl, float* __restrict__ ybuf) {
  const int nt = meta[25];
  const int total = nt * (DDIM / 128);
  const int bid = blockIdx.x;
  if (bid >= total) return;
  const int j = xcd_swz(bid, total);
  const int ct = j / nt;
  const int tile = tl[j - ct * nt];
  const int e = tile >> 8, rt = tile & 255;
  const int offs = meta[8 + e];
  const int n_e = meta[9 + e] - offs;
  const int tid = threadIdx.x, lane = tid & 63, wid = tid >> 6;

  __shared__ unsigned short As[2][128][64];
  __shared__ unsigned short Bs[2][128][64];

  const int rloc = tid >> 3;
  const int csw  = (((tid & 7) ^ (rloc & 7)) << 3);
  const unsigned short* gA[4];
  const unsigned short* gB[4];
  const unsigned short* w2e = w2b + (size_t)e * DDIM * IDIM;
#pragma unroll
  for (int jj = 0; jj < 4; ++jj) {
    gA[jj] = actb + (size_t)(offs + min(rt * 128 + jj * 32 + rloc, n_e - 1)) * IDIM + csw;
    gB[jj] = w2e + (size_t)(ct * 128 + jj * 32 + rloc) * IDIM + csw;
  }

#define G2_STAGE(BUF, KT)                                                      \
  _Pragma("unroll") for (int jj = 0; jj < 4; ++jj) {                           \
    gl2lds16(gA[jj] + (KT) * 64, &As[BUF][0][0] + jj * 2048 + tid * 8);        \
    gl2lds16(gB[jj] + (KT) * 64, &Bs[BUF][0][0] + jj * 2048 + tid * 8);        \
  }

  f32x4 acc[4][4];
#pragma unroll
  for (int m = 0; m < 4; ++m)
#pragma unroll
    for (int n = 0; n < 4; ++n) acc[m][n] = (f32x4){0.f, 0.f, 0.f, 0.f};

  const int wr = wid >> 1, wc = wid & 1;
  const int lrow = lane & 15, ksub = (lane >> 4) * 8;
  const int NK = IDIM / 64;

  G2_STAGE(0, 0)
  __syncthreads();

  int cur = 0;
  for (int kt = 0; kt < NK; ++kt) {
    if (kt + 1 < NK) { G2_STAGE(cur ^ 1, kt + 1) }
#pragma unroll
    for (int kk = 0; kk < 2; ++kk) {
      bf16x8 af[4], bfr[4];
#pragma unroll
      for (int m = 0; m < 4; ++m) {
        int row = wr * 64 + m * 16 + lrow;
        int chunk = ((kk * 32 + ksub) >> 3) ^ (row & 7);
        af[m] = *(const bf16x8*)&As[cur][row][chunk * 8];
      }
#pragma unroll
      for (int n = 0; n < 4; ++n) {
        int row = wc * 64 + n * 16 + lrow;
        int chunk = ((kk * 32 + ksub) >> 3) ^ (row & 7);
        bfr[n] = *(const bf16x8*)&Bs[cur][row][chunk * 8];
      }
#pragma unroll
      for (int m = 0; m < 4; ++m)
#pragma unroll
        for (int n = 0; n < 4; ++n)
          acc[m][n] = __builtin_amdgcn_mfma_f32_16x16x32_bf16(af[m], bfr[n], acc[m][n], 0, 0, 0);
    }
    __syncthreads();
    cur ^= 1;
  }
#undef G2_STAGE

  const float* b2e = mlp2_b + e * DDIM;
#pragma unroll
  for (int m = 0; m < 4; ++m) {
#pragma unroll
    for (int n = 0; n < 4; ++n) {
      int d = ct * 128 + wc * 64 + n * 16 + (lane & 15);
      float bias = b2e[d];
#pragma unroll
      for (int j2 = 0; j2 < 4; ++j2) {
        int rl = wr * 64 + m * 16 + ((lane >> 4) << 2) + j2;
        if (rt * 128 + rl < n_e)
          ybuf[(size_t)(offs + rt * 128 + rl) * DDIM + d] = acc[m][n][j2] + bias;
      }
    }
  }
}

// ---------------- K6: combine (deterministic, no atomics) ----------------
__global__ __launch_bounds__(256) void k_combine(
    const float* __restrict__ x, const float* __restrict__ ybuf,
    const int* __restrict__ sof, const float* __restrict__ twt,
    float* __restrict__ out) {
  int t = blockIdx.x, tid = threadIdx.x;
  int s0 = sof[2 * t], s1 = sof[2 * t + 1];
  float w0 = twt[2 * t], w1 = twt[2 * t + 1];
  float4 xv = ((const float4*)x)[t * 256 + tid];
  float4 y0 = ((const float4*)ybuf)[(size_t)s0 * 256 + tid];
  float4 y1 = ((const float4*)ybuf)[(size_t)s1 * 256 + tid];
  float4 o;
  o.x = xv.x + w0 * y0.x + w1 * y1.x;
  o.y = xv.y + w0 * y0.y + w1 * y1.y;
  o.z = xv.z + w0 * y0.z + w1 * y1.z;
  o.w = xv.w + w0 * y0.w + w1 * y1.w;
  ((float4*)out)[t * 256 + tid] = o;
}

extern "C" void kernel_launch(void* const* d_in, const int* in_sizes, int n_in,
                              void* d_out, int out_size, void* d_ws, size_t ws_size,
                              hipStream_t stream) {
  const float* x      = (const float*)d_in[0];
  const float* norm_w = (const float*)d_in[1];
  const float* gate_w = (const float*)d_in[2];
  const float* gate_b = (const float*)d_in[3];
  const float* mlp1_w = (const float*)d_in[4];
  const float* mlp1_b = (const float*)d_in[5];
  const float* mlp2_w = (const float*)d_in[6];
  const float* mlp2_b = (const float*)d_in[7];
  float* out = (float*)d_out;

  char* w = (char*)d_ws;
  unsigned short* w1b = (unsigned short*)w; w += (size_t)NEXP * TWOI * DDIM * 2;
  unsigned short* w2b = (unsigned short*)w; w += (size_t)NEXP * DDIM * IDIM * 2;
  unsigned short* hb  = (unsigned short*)w; w += (size_t)TNUM * DDIM * 2;
  unsigned short* actb = (unsigned short*)w; w += (size_t)TNUM * KSEL * IDIM * 2;
  float* ybuf = (float*)w; w += (size_t)TNUM * KSEL * DDIM * 4;
  int*   tidx = (int*)w;  w += TNUM * KSEL * 4;
  float* twt  = (float*)w; w += TNUM * KSEL * 4;
  int*   sof  = (int*)w;  w += TNUM * KSEL * 4;
  int*   rows = (int*)w;  w += TNUM * KSEL * 4;
  int*   meta = (int*)w;  w += 32 * 4;
  int*   tl   = (int*)w;  w += 64 * 4;

  hipMemsetAsync(meta, 0, 32 * 4, stream);
  k_cvt<<<(NEXP * DDIM * IDIM / 8 + 255) / 256, 256, 0, stream>>>(mlp2_w, w2b, NEXP * DDIM * IDIM / 8);
  k_cvt<<<(NEXP * TWOI * DDIM / 8 + 255) / 256, 256, 0, stream>>>(mlp1_w, w1b, NEXP * TWOI * DDIM / 8);
  k_rms_gate<<<TNUM, 256, 0, stream>>>(x, norm_w, gate_w, gate_b, hb, tidx, twt, meta);
  k_scan<<<1, 1, 0, stream>>>(meta, tl);
  k_assign<<<(TNUM + 255) / 256, 256, 0, stream>>>(tidx, meta, rows, sof);
  k_gemm1<<<dim3(ROWT_MAX * (TWOI / 128)), 256, 0, stream>>>(hb, w1b, mlp1_b, meta, tl, rows, actb);
  k_gemm2<<<dim3(ROWT_MAX * (DDIM / 128)), 256, 0, stream>>>(actb, w2b, mlp2_b, meta, tl, ybuf);
  k_combine<<<TNUM, 256, 0, stream>>>(x, ybuf, sof, twt, out);
}

// Round 5
// 112.684 us; speedup vs baseline: 1.5549x; 1.5549x over previous
//
#include <hip/hip_runtime.h>
#include <stdint.h>

#define TNUM 2048
#define DDIM 1024
#define NEXP 8
#define KSEL 2
#define IDIM 1024
#define TWOI 2048
#define LIMITV 7.0f
#define ALPHAV 1.702f
#define ROWT_MAX 40   // sum_e ceil(n_e/128) <= 40

typedef __attribute__((ext_vector_type(8))) short bf16x8;
typedef __attribute__((ext_vector_type(4))) float f32x4;

__device__ __forceinline__ unsigned short f2bf(float f) {
  unsigned u = __float_as_uint(f);
  u += 0x7FFF + ((u >> 16) & 1);   // round-to-nearest-even
  return (unsigned short)(u >> 16);
}

__device__ __forceinline__ int4 cvt8(float4 a, float4 b) {
  union { unsigned short us[8]; int4 v; } o;
  o.us[0] = f2bf(a.x); o.us[1] = f2bf(a.y); o.us[2] = f2bf(a.z); o.us[3] = f2bf(a.w);
  o.us[4] = f2bf(b.x); o.us[5] = f2bf(b.y); o.us[6] = f2bf(b.z); o.us[7] = f2bf(b.w);
  return o.v;
}

// Direct global->LDS async copy, 16B per lane (m97/m193 recipe).
__device__ __forceinline__ void gl2lds16(const void* g, void* l) {
  __builtin_amdgcn_global_load_lds(
      (__attribute__((address_space(1))) unsigned int*)(uintptr_t)g,
      (__attribute__((address_space(3))) unsigned int*)(uintptr_t)l, 16, 0, 0);
}

// Bijective chunked XCD swizzle (m204).
__device__ __forceinline__ int xcd_swz(int bid, int total) {
  int q = total >> 3, r = total & 7;
  int xcd = bid & 7, pos = bid >> 3;
  return (xcd < r ? xcd * (q + 1) : r * (q + 1) + (xcd - r) * q) + pos;
}

// ---------------- K0: fp32 -> bf16 weight conversion ----------------
__global__ __launch_bounds__(256) void k_cvt(const float* __restrict__ src,
                                             unsigned short* __restrict__ dst, int n8) {
  int i = blockIdx.x * blockDim.x + threadIdx.x;
  if (i >= n8) return;
  const float4* s = (const float4*)src;
  float4 a = s[2 * i], b = s[2 * i + 1];
  ((int4*)dst)[i] = cvt8(a, b);
}

// ---------------- K1: RMSNorm + gate logits + top-2 (wave-per-token) ----------
__global__ __launch_bounds__(256) void k_rms_gate(
    const float* __restrict__ x, const float* __restrict__ norm_w,
    const float* __restrict__ gate_w, const float* __restrict__ gate_b,
    unsigned short* __restrict__ hb, int* __restrict__ tidx,
    float* __restrict__ twt) {
  const int lane = threadIdx.x & 63;
  const int t = blockIdx.x * 4 + (threadIdx.x >> 6);

  const float4* xr  = (const float4*)x + (size_t)t * 256 + lane * 4;
  const float4* nwr = (const float4*)norm_w + lane * 4;
  const float4* gbr = (const float4*)gate_b;
  float4 xv[4], nwv[4];
#pragma unroll
  for (int i = 0; i < 4; ++i) xv[i] = xr[i];
  float4 gb0 = gbr[0], gb1 = gbr[1];
#pragma unroll
  for (int i = 0; i < 4; ++i) nwv[i] = nwr[i];

  float ss = 0.f;
#pragma unroll
  for (int i = 0; i < 4; ++i)
    ss += xv[i].x * xv[i].x + xv[i].y * xv[i].y + xv[i].z * xv[i].z + xv[i].w * xv[i].w;
#pragma unroll
  for (int m = 1; m < 64; m <<= 1) ss += __shfl_xor(ss, m);
  const float sc = rsqrtf(ss * (1.0f / DDIM) + 1.1920929e-07f);

  float4 h[4];
#pragma unroll
  for (int i = 0; i < 4; ++i) {
    h[i].x = xv[i].x * sc * nwv[i].x;
    h[i].y = xv[i].y * sc * nwv[i].y;
    h[i].z = xv[i].z * sc * nwv[i].z;
    h[i].w = xv[i].w * sc * nwv[i].w;
  }
  int4* hw = (int4*)(hb + (size_t)t * DDIM + lane * 16);
  hw[0] = cvt8(h[0], h[1]);
  hw[1] = cvt8(h[2], h[3]);

  float p[NEXP];
#pragma unroll
  for (int e = 0; e < NEXP; ++e) {
    const float4* g4 = (const float4*)gate_w + e * 256 + lane * 4;
    float4 a = g4[0], b = g4[1], c = g4[2], d = g4[3];
    p[e] = h[0].x * a.x + h[0].y * a.y + h[0].z * a.z + h[0].w * a.w
         + h[1].x * b.x + h[1].y * b.y + h[1].z * b.z + h[1].w * b.w
         + h[2].x * c.x + h[2].y * c.y + h[2].z * c.z + h[2].w * c.w
         + h[3].x * d.x + h[3].y * d.y + h[3].z * d.z + h[3].w * d.w;
  }
#pragma unroll
  for (int m = 1; m < 64; m <<= 1) {
#pragma unroll
    for (int e = 0; e < NEXP; ++e) p[e] += __shfl_xor(p[e], m);
  }
  p[0] += gb0.x; p[1] += gb0.y; p[2] += gb0.z; p[3] += gb0.w;
  p[4] += gb1.x; p[5] += gb1.y; p[6] += gb1.z; p[7] += gb1.w;

  if (lane == 0) {
    int i0 = 0; float v0 = p[0];
#pragma unroll
    for (int e = 1; e < NEXP; ++e) if (p[e] > v0) { v0 = p[e]; i0 = e; }
    int i1 = -1; float v1 = -3.4e38f;
#pragma unroll
    for (int e = 0; e < NEXP; ++e) if (e != i0 && p[e] > v1) { v1 = p[e]; i1 = e; }
    float e1 = __expf(v1 - v0);
    float w0 = 1.f / (1.f + e1);
    int2 ip; ip.x = i0; ip.y = i1;
    float2 wp; wp.x = w0; wp.y = e1 * w0;
    ((int2*)tidx)[t] = ip;
    ((float2*)twt)[t] = wp;
  }
}

// ---------------- K2: fused scheduler (single block, LDS atomics only) --------
__global__ __launch_bounds__(256) void k_sched(
    const int* __restrict__ tidx, int* __restrict__ meta,
    int* __restrict__ tl, int* __restrict__ rows, int* __restrict__ sof) {
  __shared__ int cur[NEXP];
  __shared__ int off[NEXP];
  const int tid = threadIdx.x;
  if (tid < NEXP) cur[tid] = 0;
  __syncthreads();
  int e_[16], rel_[16];
#pragma unroll
  for (int k = 0; k < 16; ++k) {
    int i = tid * 16 + k;
    int e = tidx[i];
    e_[k] = e;
    rel_[k] = atomicAdd(&cur[e], 1);
  }
  __syncthreads();
  if (tid == 0) {
    int acc = 0, nt = 0;
    for (int e = 0; e < NEXP; ++e) {
      meta[8 + e] = acc; off[e] = acc;
      int c = cur[e]; acc += c;
      int ntile = (c + 127) >> 7;
      for (int r = 0; r < ntile; ++r) tl[nt++] = (e << 8) | r;
    }
    meta[16] = acc;
    meta[25] = nt;
  }
  __syncthreads();
#pragma unroll
  for (int k = 0; k < 16; ++k) {
    int i = tid * 16 + k;
    int slot = off[e_[k]] + rel_[k];
    rows[slot] = i >> 1;
    sof[i] = slot;
  }
}

// ---------------- K4: GEMM1 (gathered A via gload_lds) + SwiGLU ----------------
__global__ __launch_bounds__(256, 2) void k_gemm1(
    const unsigned short* __restrict__ hb, const unsigned short* __restrict__ w1b,
    const float* __restrict__ mlp1_b, const int* __restrict__ meta,
    const int* __restrict__ tl, const int* __restrict__ rows,
    unsigned short* __restrict__ actb) {
  const int nt = meta[25];
  const int total = nt * (TWOI / 128);
  const int bid = blockIdx.x;
  if (bid >= total) return;
  const int j = xcd_swz(bid, total);
  const int ct = j / nt;
  const int tile = tl[j - ct * nt];
  const int e = tile >> 8, rt = tile & 255;
  const int offs = meta[8 + e];
  const int n_e = meta[9 + e] - offs;
  const int tid = threadIdx.x, lane = tid & 63, wid = tid >> 6;

  __shared__ unsigned short As[2][128][64];
  __shared__ unsigned short Bs[2][128][64];
  __shared__ int srow[128];
  if (tid < 128) srow[tid] = rows[offs + min(rt * 128 + tid, n_e - 1)];
  __syncthreads();

  const int rloc = tid >> 3;                         // 0..31
  const int csw  = (((tid & 7) ^ (rloc & 7)) << 3);  // swizzled source col (elems)
  const unsigned short* gA[4];
  const unsigned short* gB[4];
  const unsigned short* w1e = w1b + (size_t)e * TWOI * DDIM;
#pragma unroll
  for (int jj = 0; jj < 4; ++jj) {
    gA[jj] = hb + (size_t)srow[jj * 32 + rloc] * DDIM + csw;
    gB[jj] = w1e + (size_t)(ct * 128 + jj * 32 + rloc) * DDIM + csw;
  }

#define G1_STAGE(BUF, KT)                                                      \
  _Pragma("unroll") for (int jj = 0; jj < 4; ++jj) {                           \
    gl2lds16(gA[jj] + (KT) * 64, &As[BUF][0][0] + jj * 2048 + tid * 8);        \
    gl2lds16(gB[jj] + (KT) * 64, &Bs[BUF][0][0] + jj * 2048 + tid * 8);        \
  }

  f32x4 acc[4][4];
#pragma unroll
  for (int m = 0; m < 4; ++m)
#pragma unroll
    for (int n = 0; n < 4; ++n) acc[m][n] = (f32x4){0.f, 0.f, 0.f, 0.f};

  const int wr = wid >> 1, wc = wid & 1;
  const int lrow = lane & 15, ksub = (lane >> 4) * 8;
  const int NK = DDIM / 64;

  G1_STAGE(0, 0)
  __syncthreads();

  int cur = 0;
  for (int kt = 0; kt < NK; ++kt) {
    if (kt + 1 < NK) { G1_STAGE(cur ^ 1, kt + 1) }
#pragma unroll
    for (int kk = 0; kk < 2; ++kk) {
      bf16x8 af[4], bfr[4];
#pragma unroll
      for (int m = 0; m < 4; ++m) {
        int row = wr * 64 + m * 16 + lrow;
        int chunk = ((kk * 32 + ksub) >> 3) ^ (row & 7);
        af[m] = *(const bf16x8*)&As[cur][row][chunk * 8];
      }
#pragma unroll
      for (int n = 0; n < 4; ++n) {
        int row = wc * 64 + n * 16 + lrow;
        int chunk = ((kk * 32 + ksub) >> 3) ^ (row & 7);
        bfr[n] = *(const bf16x8*)&Bs[cur][row][chunk * 8];
      }
#pragma unroll
      for (int m = 0; m < 4; ++m)
#pragma unroll
        for (int n = 0; n < 4; ++n)
          acc[m][n] = __builtin_amdgcn_mfma_f32_16x16x32_bf16(af[m], bfr[n], acc[m][n], 0, 0, 0);
    }
    __syncthreads();
    cur ^= 1;
  }
#undef G1_STAGE

  const float* b1e = mlp1_b + e * TWOI;
#pragma unroll
  for (int m = 0; m < 4; ++m) {
#pragma unroll
    for (int n = 0; n < 4; ++n) {
      int cg = ct * 128 + wc * 64 + n * 16 + (lane & 15);
      float bias = b1e[cg];
#pragma unroll
      for (int j2 = 0; j2 < 4; ++j2) {
        float val = acc[m][n][j2] + bias;
        float part = __shfl_xor(val, 1);
        int rl = wr * 64 + m * 16 + ((lane >> 4) << 2) + j2;
        if (!(lane & 1)) {
          float glu = fminf(val, LIMITV);
          float lin = fminf(fmaxf(part, -LIMITV), LIMITV);
          float s = 1.f / (1.f + __expf(-ALPHAV * glu));
          float a = glu * s * (lin + 1.f);
          if (rt * 128 + rl < n_e)
            actb[(size_t)(offs + rt * 128 + rl) * IDIM + (cg >> 1)] = f2bf(a);
        }
      }
    }
  }
}

// ---------------- K5: GEMM2 (contiguous A via gload_lds) ----------------
__global__ __launch_bounds__(256, 2) void k_gemm2(
    const unsigned short* __restrict__ actb, const unsigned short* __restrict__ w2b,
    const float* __restrict__ mlp2_b, const int* __restrict__ meta,
    const int* __restrict__ tl, float* __restrict__ ybuf) {
  const int nt = meta[25];
  const int total = nt * (DDIM / 128);
  const int bid = blockIdx.x;
  if (bid >= total) return;
  const int j = xcd_swz(bid, total);
  const int ct = j / nt;
  const int tile = tl[j - ct * nt];
  const int e = tile >> 8, rt = tile & 255;
  const int offs = meta[8 + e];
  const int n_e = meta[9 + e] - offs;
  const int tid = threadIdx.x, lane = tid & 63, wid = tid >> 6;

  __shared__ unsigned short As[2][128][64];
  __shared__ unsigned short Bs[2][128][64];

  const int rloc = tid >> 3;
  const int csw  = (((tid & 7) ^ (rloc & 7)) << 3);
  const unsigned short* gA[4];
  const unsigned short* gB[4];
  const unsigned short* w2e = w2b + (size_t)e * DDIM * IDIM;
#pragma unroll
  for (int jj = 0; jj < 4; ++jj) {
    gA[jj] = actb + (size_t)(offs + min(rt * 128 + jj * 32 + rloc, n_e - 1)) * IDIM + csw;
    gB[jj] = w2e + (size_t)(ct * 128 + jj * 32 + rloc) * IDIM + csw;
  }

#define G2_STAGE(BUF, KT)                                                      \
  _Pragma("unroll") for (int jj = 0; jj < 4; ++jj) {                           \
    gl2lds16(gA[jj] + (KT) * 64, &As[BUF][0][0] + jj * 2048 + tid * 8);        \
    gl2lds16(gB[jj] + (KT) * 64, &Bs[BUF][0][0] + jj * 2048 + tid * 8);        \
  }

  f32x4 acc[4][4];
#pragma unroll
  for (int m = 0; m < 4; ++m)
#pragma unroll
    for (int n = 0; n < 4; ++n) acc[m][n] = (f32x4){0.f, 0.f, 0.f, 0.f};

  const int wr = wid >> 1, wc = wid & 1;
  const int lrow = lane & 15, ksub = (lane >> 4) * 8;
  const int NK = IDIM / 64;

  G2_STAGE(0, 0)
  __syncthreads();

  int cur = 0;
  for (int kt = 0; kt < NK; ++kt) {
    if (kt + 1 < NK) { G2_STAGE(cur ^ 1, kt + 1) }
#pragma unroll
    for (int kk = 0; kk < 2; ++kk) {
      bf16x8 af[4], bfr[4];
#pragma unroll
      for (int m = 0; m < 4; ++m) {
        int row = wr * 64 + m * 16 + lrow;
        int chunk = ((kk * 32 + ksub) >> 3) ^ (row & 7);
        af[m] = *(const bf16x8*)&As[cur][row][chunk * 8];
      }
#pragma unroll
      for (int n = 0; n < 4; ++n) {
        int row = wc * 64 + n * 16 + lrow;
        int chunk = ((kk * 32 + ksub) >> 3) ^ (row & 7);
        bfr[n] = *(const bf16x8*)&Bs[cur][row][chunk * 8];
      }
#pragma unroll
      for (int m = 0; m < 4; ++m)
#pragma unroll
        for (int n = 0; n < 4; ++n)
          acc[m][n] = __builtin_amdgcn_mfma_f32_16x16x32_bf16(af[m], bfr[n], acc[m][n], 0, 0, 0);
    }
    __syncthreads();
    cur ^= 1;
  }
#undef G2_STAGE

  const float* b2e = mlp2_b + e * DDIM;
#pragma unroll
  for (int m = 0; m < 4; ++m) {
#pragma unroll
    for (int n = 0; n < 4; ++n) {
      int d = ct * 128 + wc * 64 + n * 16 + (lane & 15);
      float bias = b2e[d];
#pragma unroll
      for (int j2 = 0; j2 < 4; ++j2) {
        int rl = wr * 64 + m * 16 + ((lane >> 4) << 2) + j2;
        if (rt * 128 + rl < n_e)
          ybuf[(size_t)(offs + rt * 128 + rl) * DDIM + d] = acc[m][n][j2] + bias;
      }
    }
  }
}

// ---------------- K6: combine (deterministic, no atomics) ----------------
__global__ __launch_bounds__(256) void k_combine(
    const float* __restrict__ x, const float* __restrict__ ybuf,
    const int* __restrict__ sof, const float* __restrict__ twt,
    float* __restrict__ out) {
  int t = blockIdx.x, tid = threadIdx.x;
  int s0 = sof[2 * t], s1 = sof[2 * t + 1];
  float w0 = twt[2 * t], w1 = twt[2 * t + 1];
  float4 xv = ((const float4*)x)[t * 256 + tid];
  float4 y0 = ((const float4*)ybuf)[(size_t)s0 * 256 + tid];
  float4 y1 = ((const float4*)ybuf)[(size_t)s1 * 256 + tid];
  float4 o;
  o.x = xv.x + w0 * y0.x + w1 * y1.x;
  o.y = xv.y + w0 * y0.y + w1 * y1.y;
  o.z = xv.z + w0 * y0.z + w1 * y1.z;
  o.w = xv.w + w0 * y0.w + w1 * y1.w;
  ((float4*)out)[t * 256 + tid] = o;
}

extern "C" void kernel_launch(void* const* d_in, const int* in_sizes, int n_in,
                              void* d_out, int out_size, void* d_ws, size_t ws_size,
                              hipStream_t stream) {
  const float* x      = (const float*)d_in[0];
  const float* norm_w = (const float*)d_in[1];
  const float* gate_w = (const float*)d_in[2];
  const float* gate_b = (const float*)d_in[3];
  const float* mlp1_w = (const float*)d_in[4];
  const float* mlp1_b = (const float*)d_in[5];
  const float* mlp2_w = (const float*)d_in[6];
  const float* mlp2_b = (const float*)d_in[7];
  float* out = (float*)d_out;

  char* w = (char*)d_ws;
  unsigned short* w1b = (unsigned short*)w; w += (size_t)NEXP * TWOI * DDIM * 2;
  unsigned short* w2b = (unsigned short*)w; w += (size_t)NEXP * DDIM * IDIM * 2;
  unsigned short* hb  = (unsigned short*)w; w += (size_t)TNUM * DDIM * 2;
  unsigned short* actb = (unsigned short*)w; w += (size_t)TNUM * KSEL * IDIM * 2;
  float* ybuf = (float*)w; w += (size_t)TNUM * KSEL * DDIM * 4;
  int*   tidx = (int*)w;  w += TNUM * KSEL * 4;
  float* twt  = (float*)w; w += TNUM * KSEL * 4;
  int*   sof  = (int*)w;  w += TNUM * KSEL * 4;
  int*   rows = (int*)w;  w += TNUM * KSEL * 4;
  int*   meta = (int*)w;  w += 32 * 4;
  int*   tl   = (int*)w;  w += 64 * 4;

  k_cvt<<<(NEXP * DDIM * IDIM / 8 + 255) / 256, 256, 0, stream>>>(mlp2_w, w2b, NEXP * DDIM * IDIM / 8);
  k_cvt<<<(NEXP * TWOI * DDIM / 8 + 255) / 256, 256, 0, stream>>>(mlp1_w, w1b, NEXP * TWOI * DDIM / 8);
  k_rms_gate<<<TNUM / 4, 256, 0, stream>>>(x, norm_w, gate_w, gate_b, hb, tidx, twt);
  k_sched<<<1, 256, 0, stream>>>(tidx, meta, tl, rows, sof);
  k_gemm1<<<dim3(ROWT_MAX * (TWOI / 128)), 256, 0, stream>>>(hb, w1b, mlp1_b, meta, tl, rows, actb);
  k_gemm2<<<dim3(ROWT_MAX * (DDIM / 128)), 256, 0, stream>>>(actb, w2b, mlp2_b, meta, tl, ybuf);
  k_combine<<<TNUM, 256, 0, stream>>>(x, ybuf, sof, twt, out);
}

// Round 6
// 110.683 us; speedup vs baseline: 1.5830x; 1.0181x over previous
//
#include <hip/hip_runtime.h>
#include <stdint.h>

#define TNUM 2048
#define DDIM 1024
#define NEXP 8
#define KSEL 2
#define IDIM 1024
#define TWOI 2048
#define LIMITV 7.0f
#define ALPHAV 1.702f
#define ROWT_MAX 40   // sum_e ceil(n_e/128) <= 40

typedef __attribute__((ext_vector_type(8))) short bf16x8;
typedef __attribute__((ext_vector_type(4))) float f32x4;

#define VMCNT8() asm volatile("s_waitcnt vmcnt(8)" ::: "memory")
#define VMCNT0() asm volatile("s_waitcnt vmcnt(0)" ::: "memory")
#define BARRIER() asm volatile("s_barrier" ::: "memory")

__device__ __forceinline__ unsigned short f2bf(float f) {
  unsigned u = __float_as_uint(f);
  u += 0x7FFF + ((u >> 16) & 1);   // round-to-nearest-even
  return (unsigned short)(u >> 16);
}

__device__ __forceinline__ int4 cvt8(float4 a, float4 b) {
  union { unsigned short us[8]; int4 v; } o;
  o.us[0] = f2bf(a.x); o.us[1] = f2bf(a.y); o.us[2] = f2bf(a.z); o.us[3] = f2bf(a.w);
  o.us[4] = f2bf(b.x); o.us[5] = f2bf(b.y); o.us[6] = f2bf(b.z); o.us[7] = f2bf(b.w);
  return o.v;
}

// Direct global->LDS async copy, 16B per lane (m97/m193 recipe).
__device__ __forceinline__ void gl2lds16(const void* g, void* l) {
  __builtin_amdgcn_global_load_lds(
      (__attribute__((address_space(1))) unsigned int*)(uintptr_t)g,
      (__attribute__((address_space(3))) unsigned int*)(uintptr_t)l, 16, 0, 0);
}

// Bijective chunked XCD swizzle (m204).
__device__ __forceinline__ int xcd_swz(int bid, int total) {
  int q = total >> 3, r = total & 7;
  int xcd = bid & 7, pos = bid >> 3;
  return (xcd < r ? xcd * (q + 1) : r * (q + 1) + (xcd - r) * q) + pos;
}

// ---------------- K0: fp32 -> bf16 conversion of both weight tensors ----------
__global__ __launch_bounds__(256) void k_cvt2(
    const float* __restrict__ w1, const float* __restrict__ w2,
    unsigned short* __restrict__ d1, unsigned short* __restrict__ d2,
    int n81, int n8tot) {
  int i = blockIdx.x * blockDim.x + threadIdx.x;
  if (i >= n8tot) return;
  const float4* s; int4* d; int k;
  if (i < n81) { s = (const float4*)w1; d = (int4*)d1; k = i; }
  else         { s = (const float4*)w2; d = (int4*)d2; k = i - n81; }
  float4 a = s[2 * k], b = s[2 * k + 1];
  d[k] = cvt8(a, b);
}

// ---------------- K1: RMSNorm + gate logits + top-2 (wave-per-token) ----------
__global__ __launch_bounds__(256) void k_rms_gate(
    const float* __restrict__ x, const float* __restrict__ norm_w,
    const float* __restrict__ gate_w, const float* __restrict__ gate_b,
    unsigned short* __restrict__ hb, int* __restrict__ tidx,
    float* __restrict__ twt) {
  const int lane = threadIdx.x & 63;
  const int t = blockIdx.x * 4 + (threadIdx.x >> 6);

  const float4* xr  = (const float4*)x + (size_t)t * 256 + lane * 4;
  const float4* nwr = (const float4*)norm_w + lane * 4;
  const float4* gbr = (const float4*)gate_b;
  float4 xv[4], nwv[4];
#pragma unroll
  for (int i = 0; i < 4; ++i) xv[i] = xr[i];
  float4 gb0 = gbr[0], gb1 = gbr[1];
#pragma unroll
  for (int i = 0; i < 4; ++i) nwv[i] = nwr[i];

  float ss = 0.f;
#pragma unroll
  for (int i = 0; i < 4; ++i)
    ss += xv[i].x * xv[i].x + xv[i].y * xv[i].y + xv[i].z * xv[i].z + xv[i].w * xv[i].w;
#pragma unroll
  for (int m = 1; m < 64; m <<= 1) ss += __shfl_xor(ss, m);
  const float sc = rsqrtf(ss * (1.0f / DDIM) + 1.1920929e-07f);

  float4 h[4];
#pragma unroll
  for (int i = 0; i < 4; ++i) {
    h[i].x = xv[i].x * sc * nwv[i].x;
    h[i].y = xv[i].y * sc * nwv[i].y;
    h[i].z = xv[i].z * sc * nwv[i].z;
    h[i].w = xv[i].w * sc * nwv[i].w;
  }
  int4* hw = (int4*)(hb + (size_t)t * DDIM + lane * 16);
  hw[0] = cvt8(h[0], h[1]);
  hw[1] = cvt8(h[2], h[3]);

  float p[NEXP];
#pragma unroll
  for (int e = 0; e < NEXP; ++e) {
    const float4* g4 = (const float4*)gate_w + e * 256 + lane * 4;
    float4 a = g4[0], b = g4[1], c = g4[2], d = g4[3];
    p[e] = h[0].x * a.x + h[0].y * a.y + h[0].z * a.z + h[0].w * a.w
         + h[1].x * b.x + h[1].y * b.y + h[1].z * b.z + h[1].w * b.w
         + h[2].x * c.x + h[2].y * c.y + h[2].z * c.z + h[2].w * c.w
         + h[3].x * d.x + h[3].y * d.y + h[3].z * d.z + h[3].w * d.w;
  }
#pragma unroll
  for (int m = 1; m < 64; m <<= 1) {
#pragma unroll
    for (int e = 0; e < NEXP; ++e) p[e] += __shfl_xor(p[e], m);
  }
  p[0] += gb0.x; p[1] += gb0.y; p[2] += gb0.z; p[3] += gb0.w;
  p[4] += gb1.x; p[5] += gb1.y; p[6] += gb1.z; p[7] += gb1.w;

  if (lane == 0) {
    int i0 = 0; float v0 = p[0];
#pragma unroll
    for (int e = 1; e < NEXP; ++e) if (p[e] > v0) { v0 = p[e]; i0 = e; }
    int i1 = -1; float v1 = -3.4e38f;
#pragma unroll
    for (int e = 0; e < NEXP; ++e) if (e != i0 && p[e] > v1) { v1 = p[e]; i1 = e; }
    float e1 = __expf(v1 - v0);
    float w0 = 1.f / (1.f + e1);
    int2 ip; ip.x = i0; ip.y = i1;
    float2 wp; wp.x = w0; wp.y = e1 * w0;
    ((int2*)tidx)[t] = ip;
    ((float2*)twt)[t] = wp;
  }
}

// ---------------- K2: fused scheduler (single block, LDS atomics only) --------
__global__ __launch_bounds__(256) void k_sched(
    const int* __restrict__ tidx, int* __restrict__ meta,
    int* __restrict__ tl, int* __restrict__ rows, int* __restrict__ sof) {
  __shared__ int cur[NEXP];
  __shared__ int off[NEXP];
  const int tid = threadIdx.x;
  if (tid < NEXP) cur[tid] = 0;
  __syncthreads();
  int e_[16], rel_[16];
#pragma unroll
  for (int k = 0; k < 16; ++k) {
    int i = tid * 16 + k;
    int e = tidx[i];
    e_[k] = e;
    rel_[k] = atomicAdd(&cur[e], 1);
  }
  __syncthreads();
  if (tid == 0) {
    int acc = 0, nt = 0;
    for (int e = 0; e < NEXP; ++e) {
      meta[8 + e] = acc; off[e] = acc;
      int c = cur[e]; acc += c;
      int ntile = (c + 127) >> 7;
      for (int r = 0; r < ntile; ++r) tl[nt++] = (e << 8) | r;
    }
    meta[16] = acc;
    meta[25] = nt;
  }
  __syncthreads();
#pragma unroll
  for (int k = 0; k < 16; ++k) {
    int i = tid * 16 + k;
    int slot = off[e_[k]] + rel_[k];
    rows[slot] = i >> 1;
    sof[i] = slot;
  }
}

// ---------------- K4: GEMM1 (gathered A via gload_lds) + SwiGLU ----------------
__global__ __launch_bounds__(256, 2) void k_gemm1(
    const unsigned short* __restrict__ hb, const unsigned short* __restrict__ w1b,
    const float* __restrict__ mlp1_b, const int* __restrict__ meta,
    const int* __restrict__ tl, const int* __restrict__ rows,
    unsigned short* __restrict__ actb) {
  const int nt = meta[25];
  const int total = nt * (TWOI / 128);
  const int bid = blockIdx.x;
  if (bid >= total) return;
  const int j = xcd_swz(bid, total);
  const int ct = j / nt;
  const int tile = tl[j - ct * nt];
  const int e = tile >> 8, rt = tile & 255;
  const int offs = meta[8 + e];
  const int n_e = meta[9 + e] - offs;
  const int tid = threadIdx.x, lane = tid & 63, wid = tid >> 6;

  __shared__ unsigned short As[2][128][64];
  __shared__ unsigned short Bs[2][128][64];
  __shared__ int srow[128];
  if (tid < 128) srow[tid] = rows[offs + min(rt * 128 + tid, n_e - 1)];
  __syncthreads();

  const int rloc = tid >> 3;                         // 0..31
  const int csw  = (((tid & 7) ^ (rloc & 7)) << 3);  // swizzled source col (elems)
  const unsigned short* gA[4];
  const unsigned short* gB[4];
  const unsigned short* w1e = w1b + (size_t)e * TWOI * DDIM;
#pragma unroll
  for (int jj = 0; jj < 4; ++jj) {
    gA[jj] = hb + (size_t)srow[jj * 32 + rloc] * DDIM + csw;
    gB[jj] = w1e + (size_t)(ct * 128 + jj * 32 + rloc) * DDIM + csw;
  }

#define G1_STAGE(BUF, KT)                                                      \
  _Pragma("unroll") for (int jj = 0; jj < 4; ++jj) {                           \
    gl2lds16(gA[jj] + (KT) * 64, &As[BUF][0][0] + jj * 2048 + tid * 8);        \
    gl2lds16(gB[jj] + (KT) * 64, &Bs[BUF][0][0] + jj * 2048 + tid * 8);        \
  }

  f32x4 acc[4][4];
#pragma unroll
  for (int m = 0; m < 4; ++m)
#pragma unroll
    for (int n = 0; n < 4; ++n) acc[m][n] = (f32x4){0.f, 0.f, 0.f, 0.f};

  const int wr = wid >> 1, wc = wid & 1;
  const int lrow = lane & 15, ksub = (lane >> 4) * 8;
  const int NK = DDIM / 64;

  G1_STAGE(0, 0)
#pragma unroll
  for (int kt = 0; kt < NK; ++kt) {
    const int cur = kt & 1;
    if (kt + 1 < NK) {
      G1_STAGE(cur ^ 1, kt + 1)
      VMCNT8();           // stage for `cur` complete; next 8 still in flight
    } else {
      VMCNT0();
    }
    BARRIER();
#pragma unroll
    for (int kk = 0; kk < 2; ++kk) {
      bf16x8 af[4], bfr[4];
#pragma unroll
      for (int m = 0; m < 4; ++m) {
        int row = wr * 64 + m * 16 + lrow;
        int chunk = ((kk * 32 + ksub) >> 3) ^ (row & 7);
        af[m] = *(const bf16x8*)&As[cur][row][chunk * 8];
      }
#pragma unroll
      for (int n = 0; n < 4; ++n) {
        int row = wc * 64 + n * 16 + lrow;
        int chunk = ((kk * 32 + ksub) >> 3) ^ (row & 7);
        bfr[n] = *(const bf16x8*)&Bs[cur][row][chunk * 8];
      }
#pragma unroll
      for (int m = 0; m < 4; ++m)
#pragma unroll
        for (int n = 0; n < 4; ++n)
          acc[m][n] = __builtin_amdgcn_mfma_f32_16x16x32_bf16(af[m], bfr[n], acc[m][n], 0, 0, 0);
    }
    BARRIER();
  }
#undef G1_STAGE

  const float* b1e = mlp1_b + e * TWOI;
#pragma unroll
  for (int m = 0; m < 4; ++m) {
#pragma unroll
    for (int n = 0; n < 4; ++n) {
      int cg = ct * 128 + wc * 64 + n * 16 + (lane & 15);
      float bias = b1e[cg];
#pragma unroll
      for (int j2 = 0; j2 < 4; ++j2) {
        float val = acc[m][n][j2] + bias;
        float part = __shfl_xor(val, 1);
        int rl = wr * 64 + m * 16 + ((lane >> 4) << 2) + j2;
        if (!(lane & 1)) {
          float glu = fminf(val, LIMITV);
          float lin = fminf(fmaxf(part, -LIMITV), LIMITV);
          float s = 1.f / (1.f + __expf(-ALPHAV * glu));
          float a = glu * s * (lin + 1.f);
          if (rt * 128 + rl < n_e)
            actb[(size_t)(offs + rt * 128 + rl) * IDIM + (cg >> 1)] = f2bf(a);
        }
      }
    }
  }
}

// ---------------- K5: GEMM2 (contiguous A via gload_lds) ----------------
__global__ __launch_bounds__(256, 2) void k_gemm2(
    const unsigned short* __restrict__ actb, const unsigned short* __restrict__ w2b,
    const float* __restrict__ mlp2_b, const int* __restrict__ meta,
    const int* __restrict__ tl, float* __restrict__ ybuf) {
  const int nt = meta[25];
  const int total = nt * (DDIM / 128);
  const int bid = blockIdx.x;
  if (bid >= total) return;
  const int j = xcd_swz(bid, total);
  const int ct = j / nt;
  const int tile = tl[j - ct * nt];
  const int e = tile >> 8, rt = tile & 255;
  const int offs = meta[8 + e];
  const int n_e = meta[9 + e] - offs;
  const int tid = threadIdx.x, lane = tid & 63, wid = tid >> 6;

  __shared__ unsigned short As[2][128][64];
  __shared__ unsigned short Bs[2][128][64];

  const int rloc = tid >> 3;
  const int csw  = (((tid & 7) ^ (rloc & 7)) << 3);
  const unsigned short* gA[4];
  const unsigned short* gB[4];
  const unsigned short* w2e = w2b + (size_t)e * DDIM * IDIM;
#pragma unroll
  for (int jj = 0; jj < 4; ++jj) {
    gA[jj] = actb + (size_t)(offs + min(rt * 128 + jj * 32 + rloc, n_e - 1)) * IDIM + csw;
    gB[jj] = w2e + (size_t)(ct * 128 + jj * 32 + rloc) * IDIM + csw;
  }

#define G2_STAGE(BUF, KT)                                                      \
  _Pragma("unroll") for (int jj = 0; jj < 4; ++jj) {                           \
    gl2lds16(gA[jj] + (KT) * 64, &As[BUF][0][0] + jj * 2048 + tid * 8);        \
    gl2lds16(gB[jj] + (KT) * 64, &Bs[BUF][0][0] + jj * 2048 + tid * 8);        \
  }

  f32x4 acc[4][4];
#pragma unroll
  for (int m = 0; m < 4; ++m)
#pragma unroll
    for (int n = 0; n < 4; ++n) acc[m][n] = (f32x4){0.f, 0.f, 0.f, 0.f};

  const int wr = wid >> 1, wc = wid & 1;
  const int lrow = lane & 15, ksub = (lane >> 4) * 8;
  const int NK = IDIM / 64;

  G2_STAGE(0, 0)
#pragma unroll
  for (int kt = 0; kt < NK; ++kt) {
    const int cur = kt & 1;
    if (kt + 1 < NK) {
      G2_STAGE(cur ^ 1, kt + 1)
      VMCNT8();
    } else {
      VMCNT0();
    }
    BARRIER();
#pragma unroll
    for (int kk = 0; kk < 2; ++kk) {
      bf16x8 af[4], bfr[4];
#pragma unroll
      for (int m = 0; m < 4; ++m) {
        int row = wr * 64 + m * 16 + lrow;
        int chunk = ((kk * 32 + ksub) >> 3) ^ (row & 7);
        af[m] = *(const bf16x8*)&As[cur][row][chunk * 8];
      }
#pragma unroll
      for (int n = 0; n < 4; ++n) {
        int row = wc * 64 + n * 16 + lrow;
        int chunk = ((kk * 32 + ksub) >> 3) ^ (row & 7);
        bfr[n] = *(const bf16x8*)&Bs[cur][row][chunk * 8];
      }
#pragma unroll
      for (int m = 0; m < 4; ++m)
#pragma unroll
        for (int n = 0; n < 4; ++n)
          acc[m][n] = __builtin_amdgcn_mfma_f32_16x16x32_bf16(af[m], bfr[n], acc[m][n], 0, 0, 0);
    }
    BARRIER();
  }
#undef G2_STAGE

  const float* b2e = mlp2_b + e * DDIM;
#pragma unroll
  for (int m = 0; m < 4; ++m) {
#pragma unroll
    for (int n = 0; n < 4; ++n) {
      int d = ct * 128 + wc * 64 + n * 16 + (lane & 15);
      float bias = b2e[d];
#pragma unroll
      for (int j2 = 0; j2 < 4; ++j2) {
        int rl = wr * 64 + m * 16 + ((lane >> 4) << 2) + j2;
        if (rt * 128 + rl < n_e)
          ybuf[(size_t)(offs + rt * 128 + rl) * DDIM + d] = acc[m][n][j2] + bias;
      }
    }
  }
}

// ---------------- K6: combine (deterministic, no atomics) ----------------
__global__ __launch_bounds__(256) void k_combine(
    const float* __restrict__ x, const float* __restrict__ ybuf,
    const int* __restrict__ sof, const float* __restrict__ twt,
    float* __restrict__ out) {
  int t = blockIdx.x, tid = threadIdx.x;
  int s0 = sof[2 * t], s1 = sof[2 * t + 1];
  float w0 = twt[2 * t], w1 = twt[2 * t + 1];
  float4 xv = ((const float4*)x)[t * 256 + tid];
  float4 y0 = ((const float4*)ybuf)[(size_t)s0 * 256 + tid];
  float4 y1 = ((const float4*)ybuf)[(size_t)s1 * 256 + tid];
  float4 o;
  o.x = xv.x + w0 * y0.x + w1 * y1.x;
  o.y = xv.y + w0 * y0.y + w1 * y1.y;
  o.z = xv.z + w0 * y0.z + w1 * y1.z;
  o.w = xv.w + w0 * y0.w + w1 * y1.w;
  ((float4*)out)[t * 256 + tid] = o;
}

extern "C" void kernel_launch(void* const* d_in, const int* in_sizes, int n_in,
                              void* d_out, int out_size, void* d_ws, size_t ws_size,
                              hipStream_t stream) {
  const float* x      = (const float*)d_in[0];
  const float* norm_w = (const float*)d_in[1];
  const float* gate_w = (const float*)d_in[2];
  const float* gate_b = (const float*)d_in[3];
  const float* mlp1_w = (const float*)d_in[4];
  const float* mlp1_b = (const float*)d_in[5];
  const float* mlp2_w = (const float*)d_in[6];
  const float* mlp2_b = (const float*)d_in[7];
  float* out = (float*)d_out;

  char* w = (char*)d_ws;
  unsigned short* w1b = (unsigned short*)w; w += (size_t)NEXP * TWOI * DDIM * 2;
  unsigned short* w2b = (unsigned short*)w; w += (size_t)NEXP * DDIM * IDIM * 2;
  unsigned short* hb  = (unsigned short*)w; w += (size_t)TNUM * DDIM * 2;
  unsigned short* actb = (unsigned short*)w; w += (size_t)TNUM * KSEL * IDIM * 2;
  float* ybuf = (float*)w; w += (size_t)TNUM * KSEL * DDIM * 4;
  int*   tidx = (int*)w;  w += TNUM * KSEL * 4;
  float* twt  = (float*)w; w += TNUM * KSEL * 4;
  int*   sof  = (int*)w;  w += TNUM * KSEL * 4;
  int*   rows = (int*)w;  w += TNUM * KSEL * 4;
  int*   meta = (int*)w;  w += 32 * 4;
  int*   tl   = (int*)w;  w += 64 * 4;

  const int n81 = NEXP * TWOI * DDIM / 8;
  const int n8tot = n81 + NEXP * DDIM * IDIM / 8;
  k_cvt2<<<(n8tot + 255) / 256, 256, 0, stream>>>(mlp1_w, mlp2_w, w1b, w2b, n81, n8tot);
  k_rms_gate<<<TNUM / 4, 256, 0, stream>>>(x, norm_w, gate_w, gate_b, hb, tidx, twt);
  k_sched<<<1, 256, 0, stream>>>(tidx, meta, tl, rows, sof);
  k_gemm1<<<dim3(ROWT_MAX * (TWOI / 128)), 256, 0, stream>>>(hb, w1b, mlp1_b, meta, tl, rows, actb);
  k_gemm2<<<dim3(ROWT_MAX * (DDIM / 128)), 256, 0, stream>>>(actb, w2b, mlp2_b, meta, tl, ybuf);
  k_combine<<<TNUM, 256, 0, stream>>>(x, ybuf, sof, twt, out);
}

// Round 8
// 103.971 us; speedup vs baseline: 1.6852x; 1.0646x over previous
//
#include <hip/hip_runtime.h>
#include <stdint.h>

#define TNUM 2048
#define DDIM 1024
#define NEXP 8
#define KSEL 2
#define IDIM 1024
#define TWOI 2048
#define LIMITV 7.0f
#define ALPHAV 1.702f
#define ROWT_MAX 40   // sum_e ceil(n_e/128) <= 40
#define RMSB (TNUM / 4)               // 512 rms blocks (wave-per-token)
#define N81 (NEXP * TWOI * DDIM / 8)  // w1 8-float groups = 2097152
#define N82 (NEXP * DDIM * IDIM / 8)  // w2 8-float groups = 1048576
#define G1TOT (ROWT_MAX * (TWOI / 128))  // 640 gemm1 tile slots

typedef __attribute__((ext_vector_type(8))) short bf16x8;
typedef __attribute__((ext_vector_type(4))) float f32x4;

#define VMCNT8() asm volatile("s_waitcnt vmcnt(8)" ::: "memory")
#define VMCNT0() asm volatile("s_waitcnt vmcnt(0)" ::: "memory")
#define BARRIER() asm volatile("s_barrier" ::: "memory")

__device__ __forceinline__ unsigned short f2bf(float f) {
  unsigned u = __float_as_uint(f);
  u += 0x7FFF + ((u >> 16) & 1);   // round-to-nearest-even
  return (unsigned short)(u >> 16);
}

__device__ __forceinline__ int4 cvt8(float4 a, float4 b) {
  union { unsigned short us[8]; int4 v; } o;
  o.us[0] = f2bf(a.x); o.us[1] = f2bf(a.y); o.us[2] = f2bf(a.z); o.us[3] = f2bf(a.w);
  o.us[4] = f2bf(b.x); o.us[5] = f2bf(b.y); o.us[6] = f2bf(b.z); o.us[7] = f2bf(b.w);
  return o.v;
}

// Direct global->LDS async copy, 16B per lane (m97/m193 recipe).
__device__ __forceinline__ void gl2lds16(const void* g, void* l) {
  __builtin_amdgcn_global_load_lds(
      (__attribute__((address_space(1))) unsigned int*)(uintptr_t)g,
      (__attribute__((address_space(3))) unsigned int*)(uintptr_t)l, 16, 0, 0);
}

// Bijective chunked XCD swizzle (m204).
__device__ __forceinline__ int xcd_swz(int bid, int total) {
  int q = total >> 3, r = total & 7;
  int xcd = bid & 7, pos = bid >> 3;
  return (xcd < r ? xcd * (q + 1) : r * (q + 1) + (xcd - r) * q) + pos;
}

// ---------------- K1: RMSNorm + gate + top-2 (wave/token) ∥ w1 fp32->bf16 -----
__global__ __launch_bounds__(256) void k_rms_cvt(
    const float* __restrict__ x, const float* __restrict__ norm_w,
    const float* __restrict__ gate_w, const float* __restrict__ gate_b,
    const float* __restrict__ w1f, unsigned short* __restrict__ w1b,
    unsigned short* __restrict__ hb, int* __restrict__ tidx,
    float* __restrict__ twt) {
  if ((int)blockIdx.x >= RMSB) {
    // weight-conversion role: one 8-float group per thread
    int k = ((int)blockIdx.x - RMSB) * 256 + (int)threadIdx.x;
    if (k < N81) {
      const float4* s = (const float4*)w1f;
      ((int4*)w1b)[k] = cvt8(s[2 * k], s[2 * k + 1]);
    }
    return;
  }
  const int lane = threadIdx.x & 63;
  const int t = blockIdx.x * 4 + (threadIdx.x >> 6);

  const float4* xr  = (const float4*)x + (size_t)t * 256 + lane * 4;
  const float4* nwr = (const float4*)norm_w + lane * 4;
  const float4* gbr = (const float4*)gate_b;
  float4 xv[4], nwv[4];
#pragma unroll
  for (int i = 0; i < 4; ++i) xv[i] = xr[i];
  float4 gb0 = gbr[0], gb1 = gbr[1];
#pragma unroll
  for (int i = 0; i < 4; ++i) nwv[i] = nwr[i];

  float ss = 0.f;
#pragma unroll
  for (int i = 0; i < 4; ++i)
    ss += xv[i].x * xv[i].x + xv[i].y * xv[i].y + xv[i].z * xv[i].z + xv[i].w * xv[i].w;
#pragma unroll
  for (int m = 1; m < 64; m <<= 1) ss += __shfl_xor(ss, m);
  const float sc = rsqrtf(ss * (1.0f / DDIM) + 1.1920929e-07f);

  float4 h[4];
#pragma unroll
  for (int i = 0; i < 4; ++i) {
    h[i].x = xv[i].x * sc * nwv[i].x;
    h[i].y = xv[i].y * sc * nwv[i].y;
    h[i].z = xv[i].z * sc * nwv[i].z;
    h[i].w = xv[i].w * sc * nwv[i].w;
  }
  int4* hw = (int4*)(hb + (size_t)t * DDIM + lane * 16);
  hw[0] = cvt8(h[0], h[1]);
  hw[1] = cvt8(h[2], h[3]);

  float p[NEXP];
#pragma unroll
  for (int e = 0; e < NEXP; ++e) {
    const float4* g4 = (const float4*)gate_w + e * 256 + lane * 4;
    float4 a = g4[0], b = g4[1], c = g4[2], d = g4[3];
    p[e] = h[0].x * a.x + h[0].y * a.y + h[0].z * a.z + h[0].w * a.w
         + h[1].x * b.x + h[1].y * b.y + h[1].z * b.z + h[1].w * b.w
         + h[2].x * c.x + h[2].y * c.y + h[2].z * c.z + h[2].w * c.w
         + h[3].x * d.x + h[3].y * d.y + h[3].z * d.z + h[3].w * d.w;
  }
#pragma unroll
  for (int m = 1; m < 64; m <<= 1) {
#pragma unroll
    for (int e = 0; e < NEXP; ++e) p[e] += __shfl_xor(p[e], m);
  }
  p[0] += gb0.x; p[1] += gb0.y; p[2] += gb0.z; p[3] += gb0.w;
  p[4] += gb1.x; p[5] += gb1.y; p[6] += gb1.z; p[7] += gb1.w;

  if (lane == 0) {
    int i0 = 0; float v0 = p[0];
#pragma unroll
    for (int e = 1; e < NEXP; ++e) if (p[e] > v0) { v0 = p[e]; i0 = e; }
    int i1 = -1; float v1 = -3.4e38f;
#pragma unroll
    for (int e = 0; e < NEXP; ++e) if (e != i0 && p[e] > v1) { v1 = p[e]; i1 = e; }
    float e1 = __expf(v1 - v0);
    float w0 = 1.f / (1.f + e1);
    int2 ip; ip.x = i0; ip.y = i1;
    float2 wp; wp.x = w0; wp.y = e1 * w0;
    ((int2*)tidx)[t] = ip;
    ((float2*)twt)[t] = wp;
  }
}

// ---------------- K2: fused scheduler (single block, LDS atomics only) --------
__global__ __launch_bounds__(256) void k_sched(
    const int* __restrict__ tidx, int* __restrict__ meta,
    int* __restrict__ tl, int* __restrict__ rows, int* __restrict__ sof) {
  __shared__ int cur[NEXP];
  __shared__ int off[NEXP];
  const int tid = threadIdx.x;
  if (tid < NEXP) cur[tid] = 0;
  __syncthreads();
  int e_[16], rel_[16];
#pragma unroll
  for (int k = 0; k < 16; ++k) {
    int i = tid * 16 + k;
    int e = tidx[i];
    e_[k] = e;
    rel_[k] = atomicAdd(&cur[e], 1);
  }
  __syncthreads();
  if (tid == 0) {
    int acc = 0, nt = 0;
    for (int e = 0; e < NEXP; ++e) {
      meta[8 + e] = acc; off[e] = acc;
      int c = cur[e]; acc += c;
      int ntile = (c + 127) >> 7;
      for (int r = 0; r < ntile; ++r) tl[nt++] = (e << 8) | r;
    }
    meta[16] = acc;
    meta[25] = nt;
  }
  __syncthreads();
#pragma unroll
  for (int k = 0; k < 16; ++k) {
    int i = tid * 16 + k;
    int slot = off[e_[k]] + rel_[k];
    rows[slot] = i >> 1;
    sof[i] = slot;
  }
}

// ---------------- K4: GEMM1 (gathered A) + SwiGLU ∥ w2 fp32->bf16 -------------
__global__ __launch_bounds__(256, 2) void k_gemm1(
    const unsigned short* __restrict__ hb, const unsigned short* __restrict__ w1b,
    const float* __restrict__ mlp1_b, const int* __restrict__ meta,
    const int* __restrict__ tl, const int* __restrict__ rows,
    const float* __restrict__ w2f, unsigned short* __restrict__ w2b,
    unsigned short* __restrict__ actb) {
  const int bid = blockIdx.x;
  const int tid = threadIdx.x, lane = tid & 63, wid = tid >> 6;
  if (bid >= G1TOT) {
    // w2 conversion role (runs while gemm tiles occupy the CUs)
    int k = (bid - G1TOT) * 256 + tid;
    if (k < N82) {
      const float4* s = (const float4*)w2f;
      ((int4*)w2b)[k] = cvt8(s[2 * k], s[2 * k + 1]);
    }
    return;
  }
  const int nt = meta[25];
  const int total = nt * (TWOI / 128);
  if (bid >= total) return;
  const int j = xcd_swz(bid, total);
  const int ct = j / nt;
  const int tile = tl[j - ct * nt];
  const int e = tile >> 8, rt = tile & 255;
  const int offs = meta[8 + e];
  const int n_e = meta[9 + e] - offs;

  __shared__ unsigned short As[2][128][64];
  __shared__ unsigned short Bs[2][128][64];
  __shared__ int srow[128];
  if (tid < 128) srow[tid] = rows[offs + min(rt * 128 + tid, n_e - 1)];
  __syncthreads();

  const int rloc = tid >> 3;                         // 0..31
  const int csw  = (((tid & 7) ^ (rloc & 7)) << 3);  // swizzled source col (elems)
  const unsigned short* gA[4];
  const unsigned short* gB[4];
  const unsigned short* w1e = w1b + (size_t)e * TWOI * DDIM;
#pragma unroll
  for (int jj = 0; jj < 4; ++jj) {
    gA[jj] = hb + (size_t)srow[jj * 32 + rloc] * DDIM + csw;
    gB[jj] = w1e + (size_t)(ct * 128 + jj * 32 + rloc) * DDIM + csw;
  }

#define G1_STAGE(BUF, KT)                                                      \
  _Pragma("unroll") for (int jj = 0; jj < 4; ++jj) {                           \
    gl2lds16(gA[jj] + (KT) * 64, &As[BUF][0][0] + jj * 2048 + tid * 8);        \
    gl2lds16(gB[jj] + (KT) * 64, &Bs[BUF][0][0] + jj * 2048 + tid * 8);        \
  }

  f32x4 acc[4][4];
#pragma unroll
  for (int m = 0; m < 4; ++m)
#pragma unroll
    for (int n = 0; n < 4; ++n) acc[m][n] = (f32x4){0.f, 0.f, 0.f, 0.f};

  const int wr = wid >> 1, wc = wid & 1;
  const int lrow = lane & 15, ksub = (lane >> 4) * 8;
  const int NK = DDIM / 64;

  G1_STAGE(0, 0)
#pragma unroll
  for (int kt = 0; kt < NK; ++kt) {
    const int cur = kt & 1;
    if (kt + 1 < NK) {
      G1_STAGE(cur ^ 1, kt + 1)
      VMCNT8();           // stage for `cur` complete; next 8 still in flight
    } else {
      VMCNT0();
    }
    BARRIER();
#pragma unroll
    for (int kk = 0; kk < 2; ++kk) {
      bf16x8 af[4], bfr[4];
#pragma unroll
      for (int m = 0; m < 4; ++m) {
        int row = wr * 64 + m * 16 + lrow;
        int chunk = ((kk * 32 + ksub) >> 3) ^ (row & 7);
        af[m] = *(const bf16x8*)&As[cur][row][chunk * 8];
      }
#pragma unroll
      for (int n = 0; n < 4; ++n) {
        int row = wc * 64 + n * 16 + lrow;
        int chunk = ((kk * 32 + ksub) >> 3) ^ (row & 7);
        bfr[n] = *(const bf16x8*)&Bs[cur][row][chunk * 8];
      }
#pragma unroll
      for (int m = 0; m < 4; ++m)
#pragma unroll
        for (int n = 0; n < 4; ++n)
          acc[m][n] = __builtin_amdgcn_mfma_f32_16x16x32_bf16(af[m], bfr[n], acc[m][n], 0, 0, 0);
    }
    BARRIER();
  }
#undef G1_STAGE

  const float* b1e = mlp1_b + e * TWOI;
#pragma unroll
  for (int m = 0; m < 4; ++m) {
#pragma unroll
    for (int n = 0; n < 4; ++n) {
      int cg = ct * 128 + wc * 64 + n * 16 + (lane & 15);
      float bias = b1e[cg];
#pragma unroll
      for (int j2 = 0; j2 < 4; ++j2) {
        float val = acc[m][n][j2] + bias;
        float part = __shfl_xor(val, 1);
        int rl = wr * 64 + m * 16 + ((lane >> 4) << 2) + j2;
        if (!(lane & 1)) {
          float glu = fminf(val, LIMITV);
          float lin = fminf(fmaxf(part, -LIMITV), LIMITV);
          float s = 1.f / (1.f + __expf(-ALPHAV * glu));
          float a = glu * s * (lin + 1.f);
          if (rt * 128 + rl < n_e)
            actb[(size_t)(offs + rt * 128 + rl) * IDIM + (cg >> 1)] = f2bf(a);
        }
      }
    }
  }
}

// ---------------- K5: GEMM2 (contiguous A via gload_lds) — round-6 verbatim ---
__global__ __launch_bounds__(256, 2) void k_gemm2(
    const unsigned short* __restrict__ actb, const unsigned short* __restrict__ w2b,
    const float* __restrict__ mlp2_b, const int* __restrict__ meta,
    const int* __restrict__ tl, float* __restrict__ ybuf) {
  const int nt = meta[25];
  const int total = nt * (DDIM / 128);
  const int bid = blockIdx.x;
  if (bid >= total) return;
  const int j = xcd_swz(bid, total);
  const int ct = j / nt;
  const int tile = tl[j - ct * nt];
  const int e = tile >> 8, rt = tile & 255;
  const int offs = meta[8 + e];
  const int n_e = meta[9 + e] - offs;
  const int tid = threadIdx.x, lane = tid & 63, wid = tid >> 6;

  __shared__ unsigned short As[2][128][64];
  __shared__ unsigned short Bs[2][128][64];

  const int rloc = tid >> 3;
  const int csw  = (((tid & 7) ^ (rloc & 7)) << 3);
  const unsigned short* gA[4];
  const unsigned short* gB[4];
  const unsigned short* w2e = w2b + (size_t)e * DDIM * IDIM;
#pragma unroll
  for (int jj = 0; jj < 4; ++jj) {
    gA[jj] = actb + (size_t)(offs + min(rt * 128 + jj * 32 + rloc, n_e - 1)) * IDIM + csw;
    gB[jj] = w2e + (size_t)(ct * 128 + jj * 32 + rloc) * IDIM + csw;
  }

#define G2_STAGE(BUF, KT)                                                      \
  _Pragma("unroll") for (int jj = 0; jj < 4; ++jj) {                           \
    gl2lds16(gA[jj] + (KT) * 64, &As[BUF][0][0] + jj * 2048 + tid * 8);        \
    gl2lds16(gB[jj] + (KT) * 64, &Bs[BUF][0][0] + jj * 2048 + tid * 8);        \
  }

  f32x4 acc[4][4];
#pragma unroll
  for (int m = 0; m < 4; ++m)
#pragma unroll
    for (int n = 0; n < 4; ++n) acc[m][n] = (f32x4){0.f, 0.f, 0.f, 0.f};

  const int wr = wid >> 1, wc = wid & 1;
  const int lrow = lane & 15, ksub = (lane >> 4) * 8;
  const int NK = IDIM / 64;

  G2_STAGE(0, 0)
#pragma unroll
  for (int kt = 0; kt < NK; ++kt) {
    const int cur = kt & 1;
    if (kt + 1 < NK) {
      G2_STAGE(cur ^ 1, kt + 1)
      VMCNT8();
    } else {
      VMCNT0();
    }
    BARRIER();
#pragma unroll
    for (int kk = 0; kk < 2; ++kk) {
      bf16x8 af[4], bfr[4];
#pragma unroll
      for (int m = 0; m < 4; ++m) {
        int row = wr * 64 + m * 16 + lrow;
        int chunk = ((kk * 32 + ksub) >> 3) ^ (row & 7);
        af[m] = *(const bf16x8*)&As[cur][row][chunk * 8];
      }
#pragma unroll
      for (int n = 0; n < 4; ++n) {
        int row = wc * 64 + n * 16 + lrow;
        int chunk = ((kk * 32 + ksub) >> 3) ^ (row & 7);
        bfr[n] = *(const bf16x8*)&Bs[cur][row][chunk * 8];
      }
#pragma unroll
      for (int m = 0; m < 4; ++m)
#pragma unroll
        for (int n = 0; n < 4; ++n)
          acc[m][n] = __builtin_amdgcn_mfma_f32_16x16x32_bf16(af[m], bfr[n], acc[m][n], 0, 0, 0);
    }
    BARRIER();
  }
#undef G2_STAGE

  const float* b2e = mlp2_b + e * DDIM;
#pragma unroll
  for (int m = 0; m < 4; ++m) {
#pragma unroll
    for (int n = 0; n < 4; ++n) {
      int d = ct * 128 + wc * 64 + n * 16 + (lane & 15);
      float bias = b2e[d];
#pragma unroll
      for (int j2 = 0; j2 < 4; ++j2) {
        int rl = wr * 64 + m * 16 + ((lane >> 4) << 2) + j2;
        if (rt * 128 + rl < n_e)
          ybuf[(size_t)(offs + rt * 128 + rl) * DDIM + d] = acc[m][n][j2] + bias;
      }
    }
  }
}

// ---------------- K6: combine (deterministic, no atomics) ----------------
__global__ __launch_bounds__(256) void k_combine(
    const float* __restrict__ x, const float* __restrict__ ybuf,
    const int* __restrict__ sof, const float* __restrict__ twt,
    float* __restrict__ out) {
  int t = blockIdx.x, tid = threadIdx.x;
  int s0 = sof[2 * t], s1 = sof[2 * t + 1];
  float w0 = twt[2 * t], w1 = twt[2 * t + 1];
  float4 xv = ((const float4*)x)[t * 256 + tid];
  float4 y0 = ((const float4*)ybuf)[(size_t)s0 * 256 + tid];
  float4 y1 = ((const float4*)ybuf)[(size_t)s1 * 256 + tid];
  float4 o;
  o.x = xv.x + w0 * y0.x + w1 * y1.x;
  o.y = xv.y + w0 * y0.y + w1 * y1.y;
  o.z = xv.z + w0 * y0.z + w1 * y1.z;
  o.w = xv.w + w0 * y0.w + w1 * y1.w;
  ((float4*)out)[t * 256 + tid] = o;
}

extern "C" void kernel_launch(void* const* d_in, const int* in_sizes, int n_in,
                              void* d_out, int out_size, void* d_ws, size_t ws_size,
                              hipStream_t stream) {
  const float* x      = (const float*)d_in[0];
  const float* norm_w = (const float*)d_in[1];
  const float* gate_w = (const float*)d_in[2];
  const float* gate_b = (const float*)d_in[3];
  const float* mlp1_w = (const float*)d_in[4];
  const float* mlp1_b = (const float*)d_in[5];
  const float* mlp2_w = (const float*)d_in[6];
  const float* mlp2_b = (const float*)d_in[7];
  float* out = (float*)d_out;

  char* w = (char*)d_ws;
  unsigned short* w1b = (unsigned short*)w; w += (size_t)NEXP * TWOI * DDIM * 2;
  unsigned short* w2b = (unsigned short*)w; w += (size_t)NEXP * DDIM * IDIM * 2;
  unsigned short* hb  = (unsigned short*)w; w += (size_t)TNUM * DDIM * 2;
  unsigned short* actb = (unsigned short*)w; w += (size_t)TNUM * KSEL * IDIM * 2;
  float* ybuf = (float*)w; w += (size_t)TNUM * KSEL * DDIM * 4;
  int*   tidx = (int*)w;  w += TNUM * KSEL * 4;
  float* twt  = (float*)w; w += TNUM * KSEL * 4;
  int*   sof  = (int*)w;  w += TNUM * KSEL * 4;
  int*   rows = (int*)w;  w += TNUM * KSEL * 4;
  int*   meta = (int*)w;  w += 32 * 4;
  int*   tl   = (int*)w;  w += 64 * 4;

  k_rms_cvt<<<RMSB + N81 / 256, 256, 0, stream>>>(x, norm_w, gate_w, gate_b,
                                                  mlp1_w, w1b, hb, tidx, twt);
  k_sched<<<1, 256, 0, stream>>>(tidx, meta, tl, rows, sof);
  k_gemm1<<<G1TOT + N82 / 256, 256, 0, stream>>>(hb, w1b, mlp1_b, meta, tl, rows,
                                                 mlp2_w, w2b, actb);
  k_gemm2<<<dim3(ROWT_MAX * (DDIM / 128)), 256, 0, stream>>>(actb, w2b, mlp2_b, meta, tl, ybuf);
  k_combine<<<TNUM, 256, 0, stream>>>(x, ybuf, sof, twt, out);
}